// Round 12
// baseline (171.072 us; speedup 1.0000x reference)
//
#include <hip/hip_runtime.h>

#define NN 50000
#define NE 800000
#define NEG_SLOPE 0.2f
#define CAP 64            // per-node bucket capacity; deg ~ Poisson(16), P(>=64) ~ 1e-19

__device__ __forceinline__ float lrelu(float v) { return v > 0.f ? v : NEG_SLOPE * v; }
__device__ __forceinline__ unsigned short f2bf(float f) {
    unsigned u = __float_as_uint(f);
    return (unsigned short)((u + 0x7FFFu + ((u >> 16) & 1u)) >> 16);   // RNE
}
__device__ __forceinline__ float rlane(float v, int l) {
    return __int_as_float(__builtin_amdgcn_readlane(__float_as_int(v), l));
}

// ============ setup: zero cnt, swizzle W1/W2, precompute w_as2/w_ad2 = W2 @ att ============
__global__ __launch_bounds__(256) void setup(const float* __restrict__ W1,
                                             const float* __restrict__ W2,
                                             const float* __restrict__ as2,
                                             const float* __restrict__ ad2,
                                             int4* __restrict__ cnt4,
                                             float* __restrict__ W1S,
                                             float* __restrict__ W2S,
                                             float* __restrict__ w_as2,
                                             float* __restrict__ w_ad2) {
    int gid = blockIdx.x * 256 + threadIdx.x;            // grid 49*256 = 12544
    if (gid < 12500) cnt4[gid] = make_int4(0, 0, 0, 0);  // 50000 ints
    if (gid < 8192) {                                    // W1 swizzle (128x64)
        int k = gid >> 6, c = gid & 63;
        W1S[((k >> 2) * 64 + c) * 4 + (k & 3)] = W1[k * 64 + c];
    } else if (gid < 12288) {                            // W2 swizzle (64x64)
        int t = gid - 8192;
        int k = t >> 6, c = t & 63;
        W2S[((k >> 2) * 64 + c) * 4 + (k & 3)] = W2[k * 64 + c];
    }
    if (gid < 64) {                                      // w_as2[k] = sum_c W2[k,c]*as2[c]
        float s = 0.f;
        for (int c = 0; c < 64; ++c) s += W2[gid * 64 + c] * as2[c];
        w_as2[gid] = s;
    } else if (gid < 128) {
        int k = gid - 64;
        float s = 0.f;
        for (int c = 0; c < 64; ++c) s += W2[k * 64 + c] * ad2[c];
        w_ad2[k] = s;
    }
}

// ============ fat kernel: blocks [0,3125) one-pass bucket build; [3125,6250) gemm1 ============
__global__ __launch_bounds__(256) void build_gemm1(const int* __restrict__ ei,
                                                   int* __restrict__ cnt,
                                                   int* __restrict__ bucket,
                                                   const float* __restrict__ x,
                                                   const float* __restrict__ W1S,
                                                   const float* __restrict__ att_s,
                                                   const float* __restrict__ att_d,
                                                   unsigned short* __restrict__ h1b,
                                                   float* __restrict__ a_s,
                                                   float2* __restrict__ nd1) {
    if (blockIdx.x < 3125) {                             // ---- CSR-free bucket build
        int e = blockIdx.x * 256 + threadIdx.x;          // exact: 3125*256 = NE
        int d = ei[NE + e];
        int pos = atomicAdd(&cnt[d], 1) & (CAP - 1);     // clamp (overflow impossible)
        bucket[d * CAP + pos] = ei[e];
        return;
    }
    // ---- gemm1 part
    int lane = threadIdx.x & 63;
    int wv   = __builtin_amdgcn_readfirstlane(threadIdx.x >> 6);
    int n0   = (blockIdx.x - 3125) * 16 + wv * 4;
    const float* __restrict__ xr = x + (size_t)n0 * 128;            // uniform ptr -> s_load
    const float4* __restrict__ wp = (const float4*)W1S;
    float4 acc = {0.f, 0.f, 0.f, 0.f};
#pragma unroll 4
    for (int k4 = 0; k4 < 32; ++k4) {
        float4 w = wp[k4 * 64 + lane];
        const float* xk = xr + k4 * 4;
        acc.x += xk[0]   * w.x + xk[1]   * w.y + xk[2]   * w.z + xk[3]   * w.w;
        acc.y += xk[128] * w.x + xk[129] * w.y + xk[130] * w.z + xk[131] * w.w;
        acc.z += xk[256] * w.x + xk[257] * w.y + xk[258] * w.z + xk[259] * w.w;
        acc.w += xk[384] * w.x + xk[385] * w.y + xk[386] * w.z + xk[387] * w.w;
    }
    float as_l = att_s[lane], ad_l = att_d[lane];
    float av[4] = {acc.x, acc.y, acc.z, acc.w};
#pragma unroll
    for (int r = 0; r < 4; ++r) {
        float a = av[r];
        h1b[(size_t)(n0 + r) * 64 + lane] = f2bf(a);
        float ps = a * as_l, pd = a * ad_l;
        ps += __shfl_xor(ps, 1, 64); pd += __shfl_xor(pd, 1, 64);
        ps += __shfl_xor(ps, 2, 64); pd += __shfl_xor(pd, 2, 64);
        ps += __shfl_xor(ps, 4, 64); pd += __shfl_xor(pd, 4, 64);
        if ((lane & 7) == 0) {
            int h = lane >> 3;
            a_s[(n0 + r) * 8 + h] = ps;
            nd1[(n0 + r) * 8 + h] = make_float2(pd, lrelu(ps + pd));
        }
    }
}

// ============ agg1: wave/node, 2-stage pipelined; writes xhb + layer-2 logits ============
__global__ __launch_bounds__(256) void agg1(const int* __restrict__ bucket,
                                            const int* __restrict__ cnt,
                                            const float* __restrict__ a_s,
                                            const float2* __restrict__ nd1,
                                            const unsigned short* __restrict__ h1b,
                                            const float* __restrict__ b1,
                                            const float* __restrict__ w_as2,
                                            const float* __restrict__ w_ad2,
                                            unsigned short* __restrict__ xhb,
                                            float* __restrict__ a_s2,
                                            float2* __restrict__ nd2) {
    int wv   = threadIdx.x >> 6;
    int lane = threadIdx.x & 63;
    int d    = blockIdx.x * 4 + wv;
    int base = d * CAP;
    int dg   = min(cnt[d], CAP);
    int sub  = lane >> 3, hch = lane & 7;
    float2 nd = nd1[d * 8 + hch];
    float acc0 = 0.f, acc1 = 0.f, acc2 = 0.f, acc3 = 0.f;
    float acc4 = 0.f, acc5 = 0.f, acc6 = 0.f, acc7 = 0.f;
    float sm = 0.f;
    int k = sub;
    int s0 = 0, s1 = 0;
    float as0 = 0.f;
    uint4 hv0 = make_uint4(0, 0, 0, 0);
    if (k < dg)     s0 = bucket[base + k];
    if (k + 8 < dg) s1 = bucket[base + k + 8];
    if (k < dg) {
        as0 = a_s[s0 * 8 + hch];
        hv0 = *(const uint4*)&h1b[(size_t)s0 * 64 + hch * 8];
    }
    for (; k < dg; k += 8) {
        int   s2  = (k + 16 < dg) ? bucket[base + k + 16] : 0;
        float as1 = 0.f;
        uint4 hv1 = make_uint4(0, 0, 0, 0);
        if (k + 8 < dg) {
            as1 = a_s[s1 * 8 + hch];
            hv1 = *(const uint4*)&h1b[(size_t)s1 * 64 + hch * 8];
        }
        float ex = __expf(lrelu(as0 + nd.x) - nd.y);
        acc0 += __uint_as_float(hv0.x << 16)          * ex;
        acc1 += __uint_as_float(hv0.x & 0xffff0000u)  * ex;
        acc2 += __uint_as_float(hv0.y << 16)          * ex;
        acc3 += __uint_as_float(hv0.y & 0xffff0000u)  * ex;
        acc4 += __uint_as_float(hv0.z << 16)          * ex;
        acc5 += __uint_as_float(hv0.z & 0xffff0000u)  * ex;
        acc6 += __uint_as_float(hv0.w << 16)          * ex;
        acc7 += __uint_as_float(hv0.w & 0xffff0000u)  * ex;
        sm += ex;
        s0 = s1; s1 = s2; as0 = as1; hv0 = hv1;
    }
    if (sub == 0) {                                    // self loop: exp(es - es) = 1
        uint4 hv = *(const uint4*)&h1b[(size_t)d * 64 + hch * 8];
        acc0 += __uint_as_float(hv.x << 16);
        acc1 += __uint_as_float(hv.x & 0xffff0000u);
        acc2 += __uint_as_float(hv.y << 16);
        acc3 += __uint_as_float(hv.y & 0xffff0000u);
        acc4 += __uint_as_float(hv.z << 16);
        acc5 += __uint_as_float(hv.z & 0xffff0000u);
        acc6 += __uint_as_float(hv.w << 16);
        acc7 += __uint_as_float(hv.w & 0xffff0000u);
        sm += 1.f;
    }
#pragma unroll
    for (int m = 8; m < 64; m <<= 1) {
        acc0 += __shfl_xor(acc0, m, 64); acc1 += __shfl_xor(acc1, m, 64);
        acc2 += __shfl_xor(acc2, m, 64); acc3 += __shfl_xor(acc3, m, 64);
        acc4 += __shfl_xor(acc4, m, 64); acc5 += __shfl_xor(acc5, m, 64);
        acc6 += __shfl_xor(acc6, m, 64); acc7 += __shfl_xor(acc7, m, 64);
        sm   += __shfl_xor(sm, m, 64);
    }
    float inv = 1.f / sm;
    int li = (lane & 7) * 8;
    float4 bl = *(const float4*)&b1[li];
    float4 bh = *(const float4*)&b1[li + 4];
    float4 lo, hi;
    lo.x = acc0 * inv + bl.x; lo.x = lo.x > 0.f ? lo.x : expm1f(lo.x);
    lo.y = acc1 * inv + bl.y; lo.y = lo.y > 0.f ? lo.y : expm1f(lo.y);
    lo.z = acc2 * inv + bl.z; lo.z = lo.z > 0.f ? lo.z : expm1f(lo.z);
    lo.w = acc3 * inv + bl.w; lo.w = lo.w > 0.f ? lo.w : expm1f(lo.w);
    hi.x = acc4 * inv + bh.x; hi.x = hi.x > 0.f ? hi.x : expm1f(hi.x);
    hi.y = acc5 * inv + bh.y; hi.y = hi.y > 0.f ? hi.y : expm1f(hi.y);
    hi.z = acc6 * inv + bh.z; hi.z = hi.z > 0.f ? hi.z : expm1f(hi.z);
    hi.w = acc7 * inv + bh.w; hi.w = hi.w > 0.f ? hi.w : expm1f(hi.w);
    if (lane < 8) {                                    // bf16 xh row (16B per lane)
        uint4 pk;
        pk.x = ((unsigned)f2bf(lo.y) << 16) | f2bf(lo.x);
        pk.y = ((unsigned)f2bf(lo.w) << 16) | f2bf(lo.z);
        pk.z = ((unsigned)f2bf(hi.y) << 16) | f2bf(hi.x);
        pk.w = ((unsigned)f2bf(hi.w) << 16) | f2bf(hi.z);
        *(uint4*)&xhb[(size_t)d * 64 + lane * 8] = pk;
    }
    // layer-2 logits: a_s2 = xh . (W2@att_s2)
    float4 s0v = *(const float4*)&w_as2[li], s1v = *(const float4*)&w_as2[li + 4];
    float4 d0v = *(const float4*)&w_ad2[li], d1v = *(const float4*)&w_ad2[li + 4];
    float ps = lo.x*s0v.x + lo.y*s0v.y + lo.z*s0v.z + lo.w*s0v.w
             + hi.x*s1v.x + hi.y*s1v.y + hi.z*s1v.z + hi.w*s1v.w;
    float pd = lo.x*d0v.x + lo.y*d0v.y + lo.z*d0v.z + lo.w*d0v.w
             + hi.x*d1v.x + hi.y*d1v.y + hi.z*d1v.z + hi.w*d1v.w;
    ps += __shfl_xor(ps, 1, 64); pd += __shfl_xor(pd, 1, 64);
    ps += __shfl_xor(ps, 2, 64); pd += __shfl_xor(pd, 2, 64);
    ps += __shfl_xor(ps, 4, 64); pd += __shfl_xor(pd, 4, 64);
    if (lane == 0) {
        a_s2[d] = ps;
        nd2[d]  = make_float2(pd, lrelu(ps + pd));
    }
}

// ============ agg2: wave/node, pipelined; applies W2 after aggregation ============
__global__ __launch_bounds__(256) void agg2(const int* __restrict__ bucket,
                                            const int* __restrict__ cnt,
                                            const float* __restrict__ a_s2,
                                            const float2* __restrict__ nd2,
                                            const unsigned short* __restrict__ xhb,
                                            const float* __restrict__ W2S,
                                            const float* __restrict__ b2,
                                            float* __restrict__ out) {
    int wv   = threadIdx.x >> 6;
    int lane = threadIdx.x & 63;
    int d    = blockIdx.x * 4 + wv;
    int base = d * CAP;
    int dg   = min(cnt[d], CAP);
    int sub  = lane >> 3, hch = lane & 7;
    float2 nd = nd2[d];
    float acc0 = 0.f, acc1 = 0.f, acc2 = 0.f, acc3 = 0.f;
    float acc4 = 0.f, acc5 = 0.f, acc6 = 0.f, acc7 = 0.f;
    float sm = 0.f;
    int k = sub;
    int s0 = 0, s1 = 0;
    float as0 = 0.f;
    uint4 hv0 = make_uint4(0, 0, 0, 0);
    if (k < dg)     s0 = bucket[base + k];
    if (k + 8 < dg) s1 = bucket[base + k + 8];
    if (k < dg) {
        as0 = a_s2[s0];
        hv0 = *(const uint4*)&xhb[(size_t)s0 * 64 + hch * 8];
    }
    for (; k < dg; k += 8) {
        int   s2  = (k + 16 < dg) ? bucket[base + k + 16] : 0;
        float as1 = 0.f;
        uint4 hv1 = make_uint4(0, 0, 0, 0);
        if (k + 8 < dg) {
            as1 = a_s2[s1];
            hv1 = *(const uint4*)&xhb[(size_t)s1 * 64 + hch * 8];
        }
        float ex = __expf(lrelu(as0 + nd.x) - nd.y);
        acc0 += __uint_as_float(hv0.x << 16)          * ex;
        acc1 += __uint_as_float(hv0.x & 0xffff0000u)  * ex;
        acc2 += __uint_as_float(hv0.y << 16)          * ex;
        acc3 += __uint_as_float(hv0.y & 0xffff0000u)  * ex;
        acc4 += __uint_as_float(hv0.z << 16)          * ex;
        acc5 += __uint_as_float(hv0.z & 0xffff0000u)  * ex;
        acc6 += __uint_as_float(hv0.w << 16)          * ex;
        acc7 += __uint_as_float(hv0.w & 0xffff0000u)  * ex;
        sm += ex;
        s0 = s1; s1 = s2; as0 = as1; hv0 = hv1;
    }
    if (sub == 0) {
        uint4 hv = *(const uint4*)&xhb[(size_t)d * 64 + hch * 8];
        acc0 += __uint_as_float(hv.x << 16);
        acc1 += __uint_as_float(hv.x & 0xffff0000u);
        acc2 += __uint_as_float(hv.y << 16);
        acc3 += __uint_as_float(hv.y & 0xffff0000u);
        acc4 += __uint_as_float(hv.z << 16);
        acc5 += __uint_as_float(hv.z & 0xffff0000u);
        acc6 += __uint_as_float(hv.w << 16);
        acc7 += __uint_as_float(hv.w & 0xffff0000u);
        sm += 1.f;
    }
#pragma unroll
    for (int m = 8; m < 64; m <<= 1) {
        acc0 += __shfl_xor(acc0, m, 64); acc1 += __shfl_xor(acc1, m, 64);
        acc2 += __shfl_xor(acc2, m, 64); acc3 += __shfl_xor(acc3, m, 64);
        acc4 += __shfl_xor(acc4, m, 64); acc5 += __shfl_xor(acc5, m, 64);
        acc6 += __shfl_xor(acc6, m, 64); acc7 += __shfl_xor(acc7, m, 64);
        sm   += __shfl_xor(sm, m, 64);
    }
    // lane L holds agg total t[(L&7)*8 + r] in acc_r; normalize then apply W2
    float inv = 1.f / sm;
    float t0 = acc0 * inv, t1 = acc1 * inv, t2 = acc2 * inv, t3 = acc3 * inv;
    float t4 = acc4 * inv, t5 = acc5 * inv, t6 = acc6 * inv, t7 = acc7 * inv;
    const float4* wp = (const float4*)W2S;
    float o = 0.f;
#pragma unroll
    for (int k4 = 0; k4 < 16; ++k4) {                  // k = 4*k4 + j, octet = k4>>1
        float4 w = wp[k4 * 64 + lane];
        int j = k4 >> 1;
        if (k4 & 1)
            o += rlane(t4, j) * w.x + rlane(t5, j) * w.y + rlane(t6, j) * w.z + rlane(t7, j) * w.w;
        else
            o += rlane(t0, j) * w.x + rlane(t1, j) * w.y + rlane(t2, j) * w.z + rlane(t3, j) * w.w;
    }
    out[(size_t)d * 64 + lane] = o + b2[lane];
}

extern "C" void kernel_launch(void* const* d_in, const int* in_sizes, int n_in,
                              void* d_out, int out_size, void* d_ws, size_t ws_size,
                              hipStream_t stream) {
    const float* x   = (const float*)d_in[0];
    const int*   ei  = (const int*)d_in[1];
    const float* W1  = (const float*)d_in[2];
    const float* as1 = (const float*)d_in[3];
    const float* ad1 = (const float*)d_in[4];
    const float* b1  = (const float*)d_in[5];
    const float* W2  = (const float*)d_in[6];
    const float* as2 = (const float*)d_in[7];
    const float* ad2 = (const float*)d_in[8];
    const float* b2  = (const float*)d_in[9];
    float* out = (float*)d_out;

    float* ws = (float*)d_ws;
    unsigned short* h1b = (unsigned short*)ws;             // 3.2M ushort  [0,1.6M)
    unsigned short* xhb = (unsigned short*)(ws + 1600000); // 3.2M ushort  [1.6M,3.2M)
    float*  a_s1 = ws + 3200000;             // 400k
    float2* nd1  = (float2*)(ws + 3600000);  // 400k float2 (800k floats)
    float*  a_s2 = ws + 4400000;             // 50k
    float2* nd2  = (float2*)(ws + 4450000);  // 50k float2 (100k floats)
    int* cnt     = (int*)(ws + 4550000);     // 50k
    int* bucket  = cnt + 50000;              // 3.2M (50k * 64)
    float* W1S   = (float*)(bucket + 3200000); // 8192
    float* W2S   = W1S + 8192;               // 4096
    float* w_as2 = W2S + 4096;               // 64
    float* w_ad2 = w_as2 + 64;               // 64

    // ---- setup, then fat bucket-build ∥ gemm1 (single-pass CSR-free graph build)
    setup<<<49, 256, 0, stream>>>(W1, W2, as2, ad2, (int4*)cnt, W1S, W2S, w_as2, w_ad2);
    build_gemm1<<<6250, 256, 0, stream>>>(ei, cnt, bucket, x, W1S, as1, ad1,
                                          h1b, a_s1, nd1);
    // ---- layer 1 aggregate (emits bf16 xh + layer-2 logits)
    agg1<<<12500, 256, 0, stream>>>(bucket, cnt, a_s1, nd1, h1b, b1,
                                    w_as2, w_ad2, xhb, a_s2, nd2);
    // ---- layer 2 aggregate with post-aggregation W2
    agg2<<<12500, 256, 0, stream>>>(bucket, cnt, a_s2, nd2, xhb, W2S, b2, out);
}

// Round 13
// 159.557 us; speedup vs baseline: 1.0722x; 1.0722x over previous
//
#include <hip/hip_runtime.h>

#define NN 50000
#define NE 800000
#define NEG_SLOPE 0.2f
#define S4 200192         // 782 blocks * 256 threads; 4 edges/thread strided by S4

__device__ __forceinline__ float lrelu(float v) { return v > 0.f ? v : NEG_SLOPE * v; }
__device__ __forceinline__ unsigned short f2bf(float f) {
    unsigned u = __float_as_uint(f);
    return (unsigned short)((u + 0x7FFFu + ((u >> 16) & 1u)) >> 16);   // RNE
}
__device__ __forceinline__ float rlane(float v, int l) {
    return __int_as_float(__builtin_amdgcn_readlane(__float_as_int(v), l));
}

// ============ setup: zero deg+cursor, swizzle W1/W2, precompute w_as2/w_ad2 = W2 @ att ============
__global__ __launch_bounds__(256) void setup(const float* __restrict__ W1,
                                             const float* __restrict__ W2,
                                             const float* __restrict__ as2,
                                             const float* __restrict__ ad2,
                                             int4* __restrict__ deg4,
                                             int* __restrict__ gcursor,
                                             float* __restrict__ W1S,
                                             float* __restrict__ W2S,
                                             float* __restrict__ w_as2,
                                             float* __restrict__ w_ad2) {
    int gid = blockIdx.x * 256 + threadIdx.x;            // grid 49*256 = 12544
    if (gid < 12500) deg4[gid] = make_int4(0, 0, 0, 0);  // 50000 ints
    if (gid == 0) *gcursor = 0;
    if (gid < 8192) {                                    // W1 swizzle (128x64)
        int k = gid >> 6, c = gid & 63;
        W1S[((k >> 2) * 64 + c) * 4 + (k & 3)] = W1[k * 64 + c];
    } else if (gid < 12288) {                            // W2 swizzle (64x64)
        int t = gid - 8192;
        int k = t >> 6, c = t & 63;
        W2S[((k >> 2) * 64 + c) * 4 + (k & 3)] = W2[k * 64 + c];
    }
    if (gid < 64) {                                      // w_as2[k] = sum_c W2[k,c]*as2[c]
        float s = 0.f;
        for (int c = 0; c < 64; ++c) s += W2[gid * 64 + c] * as2[c];
        w_as2[gid] = s;
    } else if (gid < 128) {
        int k = gid - 64;
        float s = 0.f;
        for (int c = 0; c < 64; ++c) s += W2[k * 64 + c] * ad2[c];
        w_ad2[k] = s;
    }
}

// ============ hist4: ILP-4 atomic histogram + rank (4 independent chains/thread) ============
__global__ __launch_bounds__(256) void hist4(const int* __restrict__ ei,
                                             int* __restrict__ deg,
                                             int* __restrict__ rank) {
    int tid = blockIdx.x * 256 + threadIdx.x;            // grid 782*256 = S4
    int e0 = tid, e1 = tid + S4, e2 = tid + 2 * S4, e3 = tid + 3 * S4;
    bool p3 = e3 < NE;                                   // e0..e2 always valid
    int d0 = ei[NE + e0];
    int d1 = ei[NE + e1];
    int d2 = ei[NE + e2];
    int d3 = p3 ? ei[NE + e3] : 0;
    int r0 = atomicAdd(&deg[d0], 1);
    int r1 = atomicAdd(&deg[d1], 1);
    int r2 = atomicAdd(&deg[d2], 1);
    int r3 = p3 ? atomicAdd(&deg[d3], 1) : 0;
    rank[e0] = r0;
    rank[e1] = r1;
    rank[e2] = r2;
    if (p3) rank[e3] = r3;
}

// ============ scanA: offs via block-local prefix + atomic block base ============
__global__ __launch_bounds__(256) void scanA(const int* __restrict__ deg,
                                             int* __restrict__ offs,
                                             int* __restrict__ gcursor) {
    __shared__ int tmp[256];
    __shared__ int base;
    int i = blockIdx.x * 256 + threadIdx.x;
    int v = (i < NN) ? deg[i] : 0;
    tmp[threadIdx.x] = v;
    __syncthreads();
    for (int o = 1; o < 256; o <<= 1) {
        int t = (threadIdx.x >= o) ? tmp[threadIdx.x - o] : 0;
        __syncthreads();
        tmp[threadIdx.x] += t;
        __syncthreads();
    }
    if (threadIdx.x == 255) base = atomicAdd(gcursor, tmp[255]);
    __syncthreads();
    if (i < NN) offs[i] = base + tmp[threadIdx.x] - v;   // global exclusive offset
}

// ============ fat kernel: blocks [0,782) ILP-4 scatter; [782,3907) gemm1 ============
__global__ __launch_bounds__(256) void scatter_gemm1(const int* __restrict__ ei,
                                                     const int* __restrict__ rank,
                                                     const int* __restrict__ offs,
                                                     int* __restrict__ srclist,
                                                     const float* __restrict__ x,
                                                     const float* __restrict__ W1S,
                                                     const float* __restrict__ att_s,
                                                     const float* __restrict__ att_d,
                                                     unsigned short* __restrict__ h1b,
                                                     float* __restrict__ a_s,
                                                     float2* __restrict__ nd1) {
    if (blockIdx.x < 782) {                              // ---- scatter, 4 edges/thread
        int tid = blockIdx.x * 256 + threadIdx.x;
        int e0 = tid, e1 = tid + S4, e2 = tid + 2 * S4, e3 = tid + 3 * S4;
        bool p3 = e3 < NE;
        int s0 = ei[e0], d0 = ei[NE + e0], r0 = rank[e0];
        int s1 = ei[e1], d1 = ei[NE + e1], r1 = rank[e1];
        int s2 = ei[e2], d2 = ei[NE + e2], r2 = rank[e2];
        int s3 = 0, d3 = 0, r3 = 0;
        if (p3) { s3 = ei[e3]; d3 = ei[NE + e3]; r3 = rank[e3]; }
        int o0 = offs[d0], o1 = offs[d1], o2 = offs[d2];
        int o3 = p3 ? offs[d3] : 0;
        srclist[o0 + r0] = s0;
        srclist[o1 + r1] = s1;
        srclist[o2 + r2] = s2;
        if (p3) srclist[o3 + r3] = s3;
        return;
    }
    // ---- gemm1 part
    int lane = threadIdx.x & 63;
    int wv   = __builtin_amdgcn_readfirstlane(threadIdx.x >> 6);
    int n0   = (blockIdx.x - 782) * 16 + wv * 4;
    const float* __restrict__ xr = x + (size_t)n0 * 128;            // uniform ptr -> s_load
    const float4* __restrict__ wp = (const float4*)W1S;
    float4 acc = {0.f, 0.f, 0.f, 0.f};
#pragma unroll 4
    for (int k4 = 0; k4 < 32; ++k4) {
        float4 w = wp[k4 * 64 + lane];
        const float* xk = xr + k4 * 4;
        acc.x += xk[0]   * w.x + xk[1]   * w.y + xk[2]   * w.z + xk[3]   * w.w;
        acc.y += xk[128] * w.x + xk[129] * w.y + xk[130] * w.z + xk[131] * w.w;
        acc.z += xk[256] * w.x + xk[257] * w.y + xk[258] * w.z + xk[259] * w.w;
        acc.w += xk[384] * w.x + xk[385] * w.y + xk[386] * w.z + xk[387] * w.w;
    }
    float as_l = att_s[lane], ad_l = att_d[lane];
    float av[4] = {acc.x, acc.y, acc.z, acc.w};
#pragma unroll
    for (int r = 0; r < 4; ++r) {
        float a = av[r];
        h1b[(size_t)(n0 + r) * 64 + lane] = f2bf(a);
        float ps = a * as_l, pd = a * ad_l;
        ps += __shfl_xor(ps, 1, 64); pd += __shfl_xor(pd, 1, 64);
        ps += __shfl_xor(ps, 2, 64); pd += __shfl_xor(pd, 2, 64);
        ps += __shfl_xor(ps, 4, 64); pd += __shfl_xor(pd, 4, 64);
        if ((lane & 7) == 0) {
            int h = lane >> 3;
            a_s[(n0 + r) * 8 + h] = ps;
            nd1[(n0 + r) * 8 + h] = make_float2(pd, lrelu(ps + pd));
        }
    }
}

// ============ agg1: wave/node, 2-stage pipelined; writes xhb + layer-2 logits ============
__global__ __launch_bounds__(256) void agg1(const int* __restrict__ srclist,
                                            const int* __restrict__ offs,
                                            const int* __restrict__ degv,
                                            const float* __restrict__ a_s,
                                            const float2* __restrict__ nd1,
                                            const unsigned short* __restrict__ h1b,
                                            const float* __restrict__ b1,
                                            const float* __restrict__ w_as2,
                                            const float* __restrict__ w_ad2,
                                            unsigned short* __restrict__ xhb,
                                            float* __restrict__ a_s2,
                                            float2* __restrict__ nd2) {
    int wv   = threadIdx.x >> 6;
    int lane = threadIdx.x & 63;
    int d    = blockIdx.x * 4 + wv;
    int base = offs[d], dg = degv[d];
    int sub  = lane >> 3, hch = lane & 7;
    float2 nd = nd1[d * 8 + hch];
    float acc0 = 0.f, acc1 = 0.f, acc2 = 0.f, acc3 = 0.f;
    float acc4 = 0.f, acc5 = 0.f, acc6 = 0.f, acc7 = 0.f;
    float sm = 0.f;
    int k = sub;
    int s0 = 0, s1 = 0;
    float as0 = 0.f;
    uint4 hv0 = make_uint4(0, 0, 0, 0);
    if (k < dg)     s0 = srclist[base + k];
    if (k + 8 < dg) s1 = srclist[base + k + 8];
    if (k < dg) {
        as0 = a_s[s0 * 8 + hch];
        hv0 = *(const uint4*)&h1b[(size_t)s0 * 64 + hch * 8];
    }
    for (; k < dg; k += 8) {
        int   s2  = (k + 16 < dg) ? srclist[base + k + 16] : 0;
        float as1 = 0.f;
        uint4 hv1 = make_uint4(0, 0, 0, 0);
        if (k + 8 < dg) {
            as1 = a_s[s1 * 8 + hch];
            hv1 = *(const uint4*)&h1b[(size_t)s1 * 64 + hch * 8];
        }
        float ex = __expf(lrelu(as0 + nd.x) - nd.y);
        acc0 += __uint_as_float(hv0.x << 16)          * ex;
        acc1 += __uint_as_float(hv0.x & 0xffff0000u)  * ex;
        acc2 += __uint_as_float(hv0.y << 16)          * ex;
        acc3 += __uint_as_float(hv0.y & 0xffff0000u)  * ex;
        acc4 += __uint_as_float(hv0.z << 16)          * ex;
        acc5 += __uint_as_float(hv0.z & 0xffff0000u)  * ex;
        acc6 += __uint_as_float(hv0.w << 16)          * ex;
        acc7 += __uint_as_float(hv0.w & 0xffff0000u)  * ex;
        sm += ex;
        s0 = s1; s1 = s2; as0 = as1; hv0 = hv1;
    }
    if (sub == 0) {                                    // self loop: exp(es - es) = 1
        uint4 hv = *(const uint4*)&h1b[(size_t)d * 64 + hch * 8];
        acc0 += __uint_as_float(hv.x << 16);
        acc1 += __uint_as_float(hv.x & 0xffff0000u);
        acc2 += __uint_as_float(hv.y << 16);
        acc3 += __uint_as_float(hv.y & 0xffff0000u);
        acc4 += __uint_as_float(hv.z << 16);
        acc5 += __uint_as_float(hv.z & 0xffff0000u);
        acc6 += __uint_as_float(hv.w << 16);
        acc7 += __uint_as_float(hv.w & 0xffff0000u);
        sm += 1.f;
    }
#pragma unroll
    for (int m = 8; m < 64; m <<= 1) {
        acc0 += __shfl_xor(acc0, m, 64); acc1 += __shfl_xor(acc1, m, 64);
        acc2 += __shfl_xor(acc2, m, 64); acc3 += __shfl_xor(acc3, m, 64);
        acc4 += __shfl_xor(acc4, m, 64); acc5 += __shfl_xor(acc5, m, 64);
        acc6 += __shfl_xor(acc6, m, 64); acc7 += __shfl_xor(acc7, m, 64);
        sm   += __shfl_xor(sm, m, 64);
    }
    float inv = 1.f / sm;
    int li = (lane & 7) * 8;
    float4 bl = *(const float4*)&b1[li];
    float4 bh = *(const float4*)&b1[li + 4];
    float4 lo, hi;
    lo.x = acc0 * inv + bl.x; lo.x = lo.x > 0.f ? lo.x : expm1f(lo.x);
    lo.y = acc1 * inv + bl.y; lo.y = lo.y > 0.f ? lo.y : expm1f(lo.y);
    lo.z = acc2 * inv + bl.z; lo.z = lo.z > 0.f ? lo.z : expm1f(lo.z);
    lo.w = acc3 * inv + bl.w; lo.w = lo.w > 0.f ? lo.w : expm1f(lo.w);
    hi.x = acc4 * inv + bh.x; hi.x = hi.x > 0.f ? hi.x : expm1f(hi.x);
    hi.y = acc5 * inv + bh.y; hi.y = hi.y > 0.f ? hi.y : expm1f(hi.y);
    hi.z = acc6 * inv + bh.z; hi.z = hi.z > 0.f ? hi.z : expm1f(hi.z);
    hi.w = acc7 * inv + bh.w; hi.w = hi.w > 0.f ? hi.w : expm1f(hi.w);
    if (lane < 8) {                                    // bf16 xh row (16B per lane)
        uint4 pk;
        pk.x = ((unsigned)f2bf(lo.y) << 16) | f2bf(lo.x);
        pk.y = ((unsigned)f2bf(lo.w) << 16) | f2bf(lo.z);
        pk.z = ((unsigned)f2bf(hi.y) << 16) | f2bf(hi.x);
        pk.w = ((unsigned)f2bf(hi.w) << 16) | f2bf(hi.z);
        *(uint4*)&xhb[(size_t)d * 64 + lane * 8] = pk;
    }
    // layer-2 logits: a_s2 = xh . (W2@att_s2)
    float4 s0v = *(const float4*)&w_as2[li], s1v = *(const float4*)&w_as2[li + 4];
    float4 d0v = *(const float4*)&w_ad2[li], d1v = *(const float4*)&w_ad2[li + 4];
    float ps = lo.x*s0v.x + lo.y*s0v.y + lo.z*s0v.z + lo.w*s0v.w
             + hi.x*s1v.x + hi.y*s1v.y + hi.z*s1v.z + hi.w*s1v.w;
    float pd = lo.x*d0v.x + lo.y*d0v.y + lo.z*d0v.z + lo.w*d0v.w
             + hi.x*d1v.x + hi.y*d1v.y + hi.z*d1v.z + hi.w*d1v.w;
    ps += __shfl_xor(ps, 1, 64); pd += __shfl_xor(pd, 1, 64);
    ps += __shfl_xor(ps, 2, 64); pd += __shfl_xor(pd, 2, 64);
    ps += __shfl_xor(ps, 4, 64); pd += __shfl_xor(pd, 4, 64);
    if (lane == 0) {
        a_s2[d] = ps;
        nd2[d]  = make_float2(pd, lrelu(ps + pd));
    }
}

// ============ agg2: wave/node, pipelined; applies W2 after aggregation ============
__global__ __launch_bounds__(256) void agg2(const int* __restrict__ srclist,
                                            const int* __restrict__ offs,
                                            const int* __restrict__ degv,
                                            const float* __restrict__ a_s2,
                                            const float2* __restrict__ nd2,
                                            const unsigned short* __restrict__ xhb,
                                            const float* __restrict__ W2S,
                                            const float* __restrict__ b2,
                                            float* __restrict__ out) {
    int wv   = threadIdx.x >> 6;
    int lane = threadIdx.x & 63;
    int d    = blockIdx.x * 4 + wv;
    int base = offs[d], dg = degv[d];
    int sub  = lane >> 3, hch = lane & 7;
    float2 nd = nd2[d];
    float acc0 = 0.f, acc1 = 0.f, acc2 = 0.f, acc3 = 0.f;
    float acc4 = 0.f, acc5 = 0.f, acc6 = 0.f, acc7 = 0.f;
    float sm = 0.f;
    int k = sub;
    int s0 = 0, s1 = 0;
    float as0 = 0.f;
    uint4 hv0 = make_uint4(0, 0, 0, 0);
    if (k < dg)     s0 = srclist[base + k];
    if (k + 8 < dg) s1 = srclist[base + k + 8];
    if (k < dg) {
        as0 = a_s2[s0];
        hv0 = *(const uint4*)&xhb[(size_t)s0 * 64 + hch * 8];
    }
    for (; k < dg; k += 8) {
        int   s2  = (k + 16 < dg) ? srclist[base + k + 16] : 0;
        float as1 = 0.f;
        uint4 hv1 = make_uint4(0, 0, 0, 0);
        if (k + 8 < dg) {
            as1 = a_s2[s1];
            hv1 = *(const uint4*)&xhb[(size_t)s1 * 64 + hch * 8];
        }
        float ex = __expf(lrelu(as0 + nd.x) - nd.y);
        acc0 += __uint_as_float(hv0.x << 16)          * ex;
        acc1 += __uint_as_float(hv0.x & 0xffff0000u)  * ex;
        acc2 += __uint_as_float(hv0.y << 16)          * ex;
        acc3 += __uint_as_float(hv0.y & 0xffff0000u)  * ex;
        acc4 += __uint_as_float(hv0.z << 16)          * ex;
        acc5 += __uint_as_float(hv0.z & 0xffff0000u)  * ex;
        acc6 += __uint_as_float(hv0.w << 16)          * ex;
        acc7 += __uint_as_float(hv0.w & 0xffff0000u)  * ex;
        sm += ex;
        s0 = s1; s1 = s2; as0 = as1; hv0 = hv1;
    }
    if (sub == 0) {
        uint4 hv = *(const uint4*)&xhb[(size_t)d * 64 + hch * 8];
        acc0 += __uint_as_float(hv.x << 16);
        acc1 += __uint_as_float(hv.x & 0xffff0000u);
        acc2 += __uint_as_float(hv.y << 16);
        acc3 += __uint_as_float(hv.y & 0xffff0000u);
        acc4 += __uint_as_float(hv.z << 16);
        acc5 += __uint_as_float(hv.z & 0xffff0000u);
        acc6 += __uint_as_float(hv.w << 16);
        acc7 += __uint_as_float(hv.w & 0xffff0000u);
        sm += 1.f;
    }
#pragma unroll
    for (int m = 8; m < 64; m <<= 1) {
        acc0 += __shfl_xor(acc0, m, 64); acc1 += __shfl_xor(acc1, m, 64);
        acc2 += __shfl_xor(acc2, m, 64); acc3 += __shfl_xor(acc3, m, 64);
        acc4 += __shfl_xor(acc4, m, 64); acc5 += __shfl_xor(acc5, m, 64);
        acc6 += __shfl_xor(acc6, m, 64); acc7 += __shfl_xor(acc7, m, 64);
        sm   += __shfl_xor(sm, m, 64);
    }
    // lane L holds agg total t[(L&7)*8 + r] in acc_r; normalize then apply W2
    float inv = 1.f / sm;
    float t0 = acc0 * inv, t1 = acc1 * inv, t2 = acc2 * inv, t3 = acc3 * inv;
    float t4 = acc4 * inv, t5 = acc5 * inv, t6 = acc6 * inv, t7 = acc7 * inv;
    const float4* wp = (const float4*)W2S;
    float o = 0.f;
#pragma unroll
    for (int k4 = 0; k4 < 16; ++k4) {                  // k = 4*k4 + j, octet = k4>>1
        float4 w = wp[k4 * 64 + lane];
        int j = k4 >> 1;
        if (k4 & 1)
            o += rlane(t4, j) * w.x + rlane(t5, j) * w.y + rlane(t6, j) * w.z + rlane(t7, j) * w.w;
        else
            o += rlane(t0, j) * w.x + rlane(t1, j) * w.y + rlane(t2, j) * w.z + rlane(t3, j) * w.w;
    }
    out[(size_t)d * 64 + lane] = o + b2[lane];
}

extern "C" void kernel_launch(void* const* d_in, const int* in_sizes, int n_in,
                              void* d_out, int out_size, void* d_ws, size_t ws_size,
                              hipStream_t stream) {
    const float* x   = (const float*)d_in[0];
    const int*   ei  = (const int*)d_in[1];
    const float* W1  = (const float*)d_in[2];
    const float* as1 = (const float*)d_in[3];
    const float* ad1 = (const float*)d_in[4];
    const float* b1  = (const float*)d_in[5];
    const float* W2  = (const float*)d_in[6];
    const float* as2 = (const float*)d_in[7];
    const float* ad2 = (const float*)d_in[8];
    const float* b2  = (const float*)d_in[9];
    float* out = (float*)d_out;

    float* ws = (float*)d_ws;
    unsigned short* h1b = (unsigned short*)ws;             // 3.2M ushort  [0,1.6M)
    unsigned short* xhb = (unsigned short*)(ws + 1600000); // 3.2M ushort  [1.6M,3.2M)
    float*  a_s1 = ws + 3200000;             // 400k
    float2* nd1  = (float2*)(ws + 3600000);  // 400k float2 (800k floats)
    float*  a_s2 = ws + 4400000;             // 50k
    float2* nd2  = (float2*)(ws + 4450000);  // 50k float2 (100k floats)
    int* deg     = (int*)(ws + 4550000);     // 50k
    int* offs    = deg + 50000;              // 50k
    int* gcursor = offs + 50000;             // 1 (+pad)
    int* rank    = gcursor + 64;             // 800k
    int* srclist = rank + 800000;            // 800k
    float* W1S   = (float*)(srclist + 800000); // 8192
    float* W2S   = W1S + 8192;               // 4096
    float* w_as2 = W2S + 4096;               // 64
    float* w_ad2 = w_as2 + 64;               // 64

    // ---- CSR build: ILP-4 hist -> scan -> (ILP-4 scatter ∥ gemm1)
    setup<<<49, 256, 0, stream>>>(W1, W2, as2, ad2, (int4*)deg, gcursor,
                                  W1S, W2S, w_as2, w_ad2);
    hist4<<<782, 256, 0, stream>>>(ei, deg, rank);
    scanA<<<196, 256, 0, stream>>>(deg, offs, gcursor);
    scatter_gemm1<<<3907, 256, 0, stream>>>(ei, rank, offs, srclist, x, W1S,
                                            as1, ad1, h1b, a_s1, nd1);

    // ---- layer 1 aggregate (emits bf16 xh + layer-2 logits)
    agg1<<<12500, 256, 0, stream>>>(srclist, offs, deg, a_s1, nd1, h1b, b1,
                                    w_as2, w_ad2, xhb, a_s2, nd2);
    // ---- layer 2 aggregate with post-aggregation W2
    agg2<<<12500, 256, 0, stream>>>(srclist, offs, deg, a_s2, nd2, xhb, W2S, b2, out);
}